// Round 9
// baseline (1132.305 us; speedup 1.0000x reference)
//
#include <hip/hip_runtime.h>
#include <stdint.h>

#define N_NODES 50000
#define N_GRAPHS 64
#define VOCAB 100000
#define DIM 256
#define N_EDGES 800000
#define T_SEQ 16
#define CAP 64   // max in-degree bucket capacity (Poisson(16) -> max deg ~40)

typedef short bf16x8 __attribute__((ext_vector_type(8)));
typedef unsigned short u16x8 __attribute__((ext_vector_type(8)));
typedef float f32x4 __attribute__((ext_vector_type(4)));
typedef unsigned short u16;

__device__ __forceinline__ float bf2f(u16 u) {
    union { unsigned int i; float f; } v; v.i = ((unsigned int)u) << 16; return v.f;
}
__device__ __forceinline__ u16 f2bf(float f) {
    union { float f; unsigned int i; } v; v.f = f;
    unsigned int x = v.i;
    return (u16)((x + 0x7fffu + ((x >> 16) & 1u)) >> 16);  // RNE, finite inputs
}

// ---- prep: cast emb f32->bf16, transpose+cast W0/W1, zero counts & out ----
__global__ __launch_bounds__(256) void prep_kernel(const float* __restrict__ emb,
        u16* __restrict__ emb_bf, const float* __restrict__ W0, u16* __restrict__ WT0,
        const float* __restrict__ W1, u16* __restrict__ WT1,
        int* __restrict__ counts, float* __restrict__ out) {
    int bid = blockIdx.x;
    if (bid < 12500) {
        size_t base = ((size_t)bid * 256 + threadIdx.x) * 8;
        float4 a = *(const float4*)(emb + base);
        float4 b = *(const float4*)(emb + base + 4);
        ushort4 o0, o1;
        o0.x = f2bf(a.x); o0.y = f2bf(a.y); o0.z = f2bf(a.z); o0.w = f2bf(a.w);
        o1.x = f2bf(b.x); o1.y = f2bf(b.y); o1.z = f2bf(b.z); o1.w = f2bf(b.w);
        *(ushort4*)(emb_bf + base) = o0;
        *(ushort4*)(emb_bf + base + 4) = o1;
        if (bid < 196) {
            int i = bid * 256 + threadIdx.x;
            if (i < N_NODES) counts[i] = 0;
        }
        if (bid < 64) out[bid * 256 + threadIdx.x] = 0.f;
    } else {
        __shared__ u16 tile[32][33];
        int b = bid - 12500;
        int which = b >> 6;
        const float* W = which ? W1 : W0;
        u16* WT = which ? WT1 : WT0;
        b &= 63;
        int bx = b & 7, by = b >> 3;
        int tx = threadIdx.x & 31, ty = threadIdx.x >> 5;  // 32x8
#pragma unroll
        for (int r = 0; r < 32; r += 8)
            tile[ty + r][tx] = f2bf(W[(size_t)(by * 32 + ty + r) * DIM + bx * 32 + tx]);
        __syncthreads();
#pragma unroll
        for (int r = 0; r < 32; r += 8)
            WT[(size_t)(bx * 32 + ty + r) * DIM + by * 32 + tx] = tile[tx][ty + r];
    }
}

// ---- bucket fill: bucket[d*CAP + p] = src, p = atomicAdd(counts[d]) ----
__global__ void fill_kernel(const int* __restrict__ src, const int* __restrict__ dst,
        int* __restrict__ counts, int* __restrict__ bucket) {
    int e = blockIdx.x * 256 + threadIdx.x;
    if (e < N_EDGES) {
        int d = dst[e];
        int p = atomicAdd(&counts[d], 1);
        if (p < CAP) bucket[(size_t)d * CAP + p] = src[e];
    }
}

// ---- encoder: x[n,:] = sum_t emb_bf[seq[n,t],:]; also writes dis[n] ----
__global__ __launch_bounds__(256) void encode_kernel(const int* __restrict__ seq,
        const u16* __restrict__ emb, const int* __restrict__ counts,
        float* __restrict__ dis, u16* __restrict__ x) {
    int wave = threadIdx.x >> 6, lane = threadIdx.x & 63;
    int n = blockIdx.x * 4 + wave;
    if (n >= N_NODES) return;
    int half = lane >> 5, l32 = lane & 31;
    int c = l32 * 8;
    float a[8] = {0.f, 0.f, 0.f, 0.f, 0.f, 0.f, 0.f, 0.f};
#pragma unroll
    for (int tt = 0; tt < 8; ++tt) {          // token t = half + 2*tt
        int tok = seq[n * T_SEQ + half + 2 * tt];
        u16x8 v = *(const u16x8*)(emb + (size_t)tok * DIM + c);
#pragma unroll
        for (int j = 0; j < 8; ++j) a[j] += bf2f(v[j]);
    }
#pragma unroll
    for (int j = 0; j < 8; ++j) a[j] += __shfl_xor(a[j], 32, 64);
    if (half == 0) {
        u16x8 o;
#pragma unroll
        for (int j = 0; j < 8; ++j) o[j] = f2bf(a[j]);
        *(u16x8*)(x + (size_t)n * DIM + c) = o;
    }
    if (lane == 0) {
        int cnt = counts[n]; if (cnt > CAP) cnt = CAP;
        dis[n] = rsqrtf((float)cnt + 1.0f);
    }
}

// ---- GEMM: C[M,256] = ((A @ W) + bias) * dis[row]  (bf16, MFMA) ----
__global__ __launch_bounds__(256) void gemm_kernel(const u16* __restrict__ A,
        const u16* __restrict__ WT, const float* __restrict__ bias,
        const float* __restrict__ dis, u16* __restrict__ C, int M) {
    __shared__ __align__(16) uint8_t ldsA[128 * 64];  // [128 rows][32 bf16] 8KB
    __shared__ __align__(16) uint8_t ldsB[128 * 64];  // [128 cols][32 bf16] 8KB
    int tid = threadIdx.x;
    int wave = tid >> 6, lane = tid & 63;
    int quad = lane >> 4, l16 = lane & 15;
    int wm = wave & 1, wn = wave >> 1;
    int bm = blockIdx.y * 128, bn = blockIdx.x * 128;

    f32x4 acc[4][4] = {};

    for (int kt = 0; kt < 8; ++kt) {
        int k0 = kt * 32;
#pragma unroll
        for (int i = 0; i < 2; ++i) {
            int chunk = tid + i * 256;          // 0..511
            int row = chunk >> 2;               // 0..127
            int coff = (chunk & 3) * 16;        // byte offset in 64B row
            int gr = bm + row; if (gr > M - 1) gr = M - 1;
            uint4 va = *(const uint4*)((const uint8_t*)A + ((size_t)gr * DIM + k0) * 2 + coff);
            *(uint4*)(ldsA + row * 64 + coff) = va;
            uint4 vb = *(const uint4*)((const uint8_t*)WT + ((size_t)(bn + row) * DIM + k0) * 2 + coff);
            *(uint4*)(ldsB + row * 64 + coff) = vb;
        }
        __syncthreads();
        bf16x8 afr[4], bfr[4];
#pragma unroll
        for (int t = 0; t < 4; ++t) {
            afr[t] = *(const bf16x8*)(ldsA + (wm * 64 + t * 16 + l16) * 64 + quad * 16);
            bfr[t] = *(const bf16x8*)(ldsB + (wn * 64 + t * 16 + l16) * 64 + quad * 16);
        }
#pragma unroll
        for (int tm = 0; tm < 4; ++tm)
#pragma unroll
            for (int tn = 0; tn < 4; ++tn)
                acc[tm][tn] = __builtin_amdgcn_mfma_f32_16x16x32_bf16(
                    afr[tm], bfr[tn], acc[tm][tn], 0, 0, 0);
        __syncthreads();
    }

    float bv[4];
#pragma unroll
    for (int tn = 0; tn < 4; ++tn) bv[tn] = bias[bn + wn * 64 + tn * 16 + l16];
#pragma unroll
    for (int tm = 0; tm < 4; ++tm) {
        int row0 = bm + wm * 64 + tm * 16 + quad * 4;
#pragma unroll
        for (int r = 0; r < 4; ++r) {
            int row = row0 + r;
            if (row < M) {
                float dsc = dis[row];
#pragma unroll
                for (int tn = 0; tn < 4; ++tn) {
                    int col = bn + wn * 64 + tn * 16 + l16;
                    C[(size_t)row * DIM + col] = f2bf((acc[tm][tn][r] + bv[tn]) * dsc);
                }
            }
        }
    }
}

// ---- agg (layer 1): z[n] = relu(dn*(sum_s h[s] + h[n])), h pre-scaled by dis ----
__global__ __launch_bounds__(256) void agg_kernel(const u16* __restrict__ h,
        const int* __restrict__ counts, const int* __restrict__ bucket,
        const float* __restrict__ dis, u16* __restrict__ z) {
    int wave = threadIdx.x >> 6, lane = threadIdx.x & 63;
    int n = blockIdx.x * 4 + wave;
    if (n >= N_NODES) return;
    int half = lane >> 5, l32 = lane & 31;
    int c = l32 * 8;
    float a[8];
    if (half == 0) {
        u16x8 v = *(const u16x8*)(h + (size_t)n * DIM + c);
#pragma unroll
        for (int j = 0; j < 8; ++j) a[j] = bf2f(v[j]);
    } else {
#pragma unroll
        for (int j = 0; j < 8; ++j) a[j] = 0.f;
    }
    int cnt = counts[n]; if (cnt > CAP) cnt = CAP;
    const int* bk = bucket + (size_t)n * CAP;
    int e = half;
    for (; e + 6 < cnt; e += 8) {
        int s0 = bk[e];
        int s1 = bk[e + 2];
        int s2 = bk[e + 4];
        int s3 = bk[e + 6];
        u16x8 v0 = *(const u16x8*)(h + (size_t)s0 * DIM + c);
        u16x8 v1 = *(const u16x8*)(h + (size_t)s1 * DIM + c);
        u16x8 v2 = *(const u16x8*)(h + (size_t)s2 * DIM + c);
        u16x8 v3 = *(const u16x8*)(h + (size_t)s3 * DIM + c);
#pragma unroll
        for (int j = 0; j < 8; ++j)
            a[j] += bf2f(v0[j]) + bf2f(v1[j]) + bf2f(v2[j]) + bf2f(v3[j]);
    }
    for (; e < cnt; e += 2) {
        int s = bk[e];
        u16x8 v = *(const u16x8*)(h + (size_t)s * DIM + c);
#pragma unroll
        for (int j = 0; j < 8; ++j) a[j] += bf2f(v[j]);
    }
#pragma unroll
    for (int j = 0; j < 8; ++j) a[j] += __shfl_xor(a[j], 32, 64);
    if (half == 0) {
        float dn = dis[n];
        u16x8 o;
#pragma unroll
        for (int j = 0; j < 8; ++j) o[j] = f2bf(fmaxf(a[j] * dn, 0.f));
        *(u16x8*)(z + (size_t)n * DIM + c) = o;
    }
}

// ---- agg (layer 2) + pool fused: out[batch[n],:] += relu(dn*(sum+self)) ----
// z2 never materialized: half-0 lanes atomicAdd 8 f32 each straight into out.
__global__ __launch_bounds__(256) void agg_pool_kernel(const u16* __restrict__ h,
        const int* __restrict__ counts, const int* __restrict__ bucket,
        const float* __restrict__ dis, const int* __restrict__ batch,
        float* __restrict__ out) {
    int wave = threadIdx.x >> 6, lane = threadIdx.x & 63;
    int n = blockIdx.x * 4 + wave;
    if (n >= N_NODES) return;
    int half = lane >> 5, l32 = lane & 31;
    int c = l32 * 8;
    float a[8];
    if (half == 0) {
        u16x8 v = *(const u16x8*)(h + (size_t)n * DIM + c);
#pragma unroll
        for (int j = 0; j < 8; ++j) a[j] = bf2f(v[j]);
    } else {
#pragma unroll
        for (int j = 0; j < 8; ++j) a[j] = 0.f;
    }
    int cnt = counts[n]; if (cnt > CAP) cnt = CAP;
    const int* bk = bucket + (size_t)n * CAP;
    int e = half;
    for (; e + 6 < cnt; e += 8) {
        int s0 = bk[e];
        int s1 = bk[e + 2];
        int s2 = bk[e + 4];
        int s3 = bk[e + 6];
        u16x8 v0 = *(const u16x8*)(h + (size_t)s0 * DIM + c);
        u16x8 v1 = *(const u16x8*)(h + (size_t)s1 * DIM + c);
        u16x8 v2 = *(const u16x8*)(h + (size_t)s2 * DIM + c);
        u16x8 v3 = *(const u16x8*)(h + (size_t)s3 * DIM + c);
#pragma unroll
        for (int j = 0; j < 8; ++j)
            a[j] += bf2f(v0[j]) + bf2f(v1[j]) + bf2f(v2[j]) + bf2f(v3[j]);
    }
    for (; e < cnt; e += 2) {
        int s = bk[e];
        u16x8 v = *(const u16x8*)(h + (size_t)s * DIM + c);
#pragma unroll
        for (int j = 0; j < 8; ++j) a[j] += bf2f(v[j]);
    }
#pragma unroll
    for (int j = 0; j < 8; ++j) a[j] += __shfl_xor(a[j], 32, 64);
    if (half == 0) {
        float dn = dis[n];
        float* og = out + (size_t)batch[n] * DIM + c;
#pragma unroll
        for (int j = 0; j < 8; ++j)
            atomicAdd(&og[j], fmaxf(a[j] * dn, 0.f));
    }
}

extern "C" void kernel_launch(void* const* d_in, const int* in_sizes, int n_in,
                              void* d_out, int out_size, void* d_ws, size_t ws_size,
                              hipStream_t stream) {
    const int*   seq   = (const int*)d_in[0];
    const int*   eidx  = (const int*)d_in[1];
    const int*   batch = (const int*)d_in[2];
    const float* emb   = (const float*)d_in[3];
    const float* W0    = (const float*)d_in[4];
    const float* b0    = (const float*)d_in[5];
    const float* W1    = (const float*)d_in[6];
    const float* b1    = (const float*)d_in[7];
    float* out = (float*)d_out;

    uint8_t* ws = (uint8_t*)d_ws;
    size_t off = 0;
    auto alloc = [&](size_t bytes) -> uint8_t* {
        uint8_t* p = ws + off;
        off += (bytes + 255) & ~(size_t)255;
        return p;
    };
    u16* emb_bf  = (u16*)alloc((size_t)VOCAB * DIM * 2);     // 51.2 MB
    u16* buf0    = (u16*)alloc((size_t)N_NODES * DIM * 2);   // 25.6 MB
    u16* buf1    = (u16*)alloc((size_t)N_NODES * DIM * 2);   // 25.6 MB
    int* bucket  = (int*)alloc((size_t)N_NODES * CAP * 4);   // 12.8 MB
    int* counts  = (int*)alloc((size_t)N_NODES * 4);
    float* dis   = (float*)alloc((size_t)N_NODES * 4);
    u16* WT0     = (u16*)alloc((size_t)DIM * DIM * 2);
    u16* WT1     = (u16*)alloc((size_t)DIM * DIM * 2);

    const int* esrc = eidx;
    const int* edst = eidx + N_EDGES;

    // 7 dispatches total
    prep_kernel<<<12500 + 128, 256, 0, stream>>>(emb, emb_bf, W0, WT0, W1, WT1,
                                                 counts, out);
    fill_kernel<<<(N_EDGES + 255) / 256, 256, 0, stream>>>(esrc, edst, counts, bucket);
    encode_kernel<<<(N_NODES + 3) / 4, 256, 0, stream>>>(seq, emb_bf, counts, dis, buf0);

    dim3 ggrid(2, (N_NODES + 127) / 128);  // (2, 391)
    gemm_kernel<<<ggrid, 256, 0, stream>>>(buf0, WT0, b0, dis, buf1, N_NODES);
    agg_kernel<<<(N_NODES + 3) / 4, 256, 0, stream>>>(buf1, counts, bucket, dis, buf0);
    gemm_kernel<<<ggrid, 256, 0, stream>>>(buf0, WT1, b1, dis, buf1, N_NODES);
    agg_pool_kernel<<<(N_NODES + 3) / 4, 256, 0, stream>>>(buf1, counts, bucket, dis,
                                                           batch, out);
}

// Round 10
// 463.584 us; speedup vs baseline: 2.4425x; 2.4425x over previous
//
#include <hip/hip_runtime.h>
#include <stdint.h>

#define N_NODES 50000
#define N_GRAPHS 64
#define VOCAB 100000
#define DIM 256
#define N_EDGES 800000
#define T_SEQ 16
#define CAP 64   // max in-degree bucket capacity (Poisson(16) -> max deg ~40)

typedef short bf16x8 __attribute__((ext_vector_type(8)));
typedef unsigned short u16x8 __attribute__((ext_vector_type(8)));
typedef float f32x4 __attribute__((ext_vector_type(4)));
typedef unsigned short u16;

__device__ __forceinline__ float bf2f(u16 u) {
    union { unsigned int i; float f; } v; v.i = ((unsigned int)u) << 16; return v.f;
}
__device__ __forceinline__ u16 f2bf(float f) {
    union { float f; unsigned int i; } v; v.f = f;
    unsigned int x = v.i;
    return (u16)((x + 0x7fffu + ((x >> 16) & 1u)) >> 16);  // RNE, finite inputs
}

// ---- prep: cast emb f32->bf16, transpose+cast W0/W1, zero counts & out ----
__global__ __launch_bounds__(256) void prep_kernel(const float* __restrict__ emb,
        u16* __restrict__ emb_bf, const float* __restrict__ W0, u16* __restrict__ WT0,
        const float* __restrict__ W1, u16* __restrict__ WT1,
        int* __restrict__ counts, float* __restrict__ out) {
    int bid = blockIdx.x;
    if (bid < 12500) {
        size_t base = ((size_t)bid * 256 + threadIdx.x) * 8;
        float4 a = *(const float4*)(emb + base);
        float4 b = *(const float4*)(emb + base + 4);
        ushort4 o0, o1;
        o0.x = f2bf(a.x); o0.y = f2bf(a.y); o0.z = f2bf(a.z); o0.w = f2bf(a.w);
        o1.x = f2bf(b.x); o1.y = f2bf(b.y); o1.z = f2bf(b.z); o1.w = f2bf(b.w);
        *(ushort4*)(emb_bf + base) = o0;
        *(ushort4*)(emb_bf + base + 4) = o1;
        if (bid < 196) {
            int i = bid * 256 + threadIdx.x;
            if (i < N_NODES) counts[i] = 0;
        }
        if (bid < 64) out[bid * 256 + threadIdx.x] = 0.f;
    } else {
        __shared__ u16 tile[32][33];
        int b = bid - 12500;
        int which = b >> 6;
        const float* W = which ? W1 : W0;
        u16* WT = which ? WT1 : WT0;
        b &= 63;
        int bx = b & 7, by = b >> 3;
        int tx = threadIdx.x & 31, ty = threadIdx.x >> 5;  // 32x8
#pragma unroll
        for (int r = 0; r < 32; r += 8)
            tile[ty + r][tx] = f2bf(W[(size_t)(by * 32 + ty + r) * DIM + bx * 32 + tx]);
        __syncthreads();
#pragma unroll
        for (int r = 0; r < 32; r += 8)
            WT[(size_t)(bx * 32 + ty + r) * DIM + by * 32 + tx] = tile[tx][ty + r];
    }
}

// ---- bucket fill: bucket[d*CAP + p] = src, p = atomicAdd(counts[d]) ----
__global__ void fill_kernel(const int* __restrict__ src, const int* __restrict__ dst,
        int* __restrict__ counts, int* __restrict__ bucket) {
    int e = blockIdx.x * 256 + threadIdx.x;
    if (e < N_EDGES) {
        int d = dst[e];
        int p = atomicAdd(&counts[d], 1);
        if (p < CAP) bucket[(size_t)d * CAP + p] = src[e];
    }
}

// ---- encoder: x[n,:] = sum_t emb_bf[seq[n,t],:]; also writes dis[n] ----
__global__ __launch_bounds__(256) void encode_kernel(const int* __restrict__ seq,
        const u16* __restrict__ emb, const int* __restrict__ counts,
        float* __restrict__ dis, u16* __restrict__ x) {
    int wave = threadIdx.x >> 6, lane = threadIdx.x & 63;
    int n = blockIdx.x * 4 + wave;
    if (n >= N_NODES) return;
    int half = lane >> 5, l32 = lane & 31;
    int c = l32 * 8;
    float a[8] = {0.f, 0.f, 0.f, 0.f, 0.f, 0.f, 0.f, 0.f};
#pragma unroll
    for (int tt = 0; tt < 8; ++tt) {          // token t = half + 2*tt
        int tok = seq[n * T_SEQ + half + 2 * tt];
        u16x8 v = *(const u16x8*)(emb + (size_t)tok * DIM + c);
#pragma unroll
        for (int j = 0; j < 8; ++j) a[j] += bf2f(v[j]);
    }
#pragma unroll
    for (int j = 0; j < 8; ++j) a[j] += __shfl_xor(a[j], 32, 64);
    if (half == 0) {
        u16x8 o;
#pragma unroll
        for (int j = 0; j < 8; ++j) o[j] = f2bf(a[j]);
        *(u16x8*)(x + (size_t)n * DIM + c) = o;
    }
    if (lane == 0) {
        int cnt = counts[n]; if (cnt > CAP) cnt = CAP;
        dis[n] = rsqrtf((float)cnt + 1.0f);
    }
}

// ---- GEMM: C[M,256] = ((A @ W) + bias) * dis[row]  (bf16, MFMA) ----
__global__ __launch_bounds__(256) void gemm_kernel(const u16* __restrict__ A,
        const u16* __restrict__ WT, const float* __restrict__ bias,
        const float* __restrict__ dis, u16* __restrict__ C, int M) {
    __shared__ __align__(16) uint8_t ldsA[128 * 64];  // [128 rows][32 bf16] 8KB
    __shared__ __align__(16) uint8_t ldsB[128 * 64];  // [128 cols][32 bf16] 8KB
    int tid = threadIdx.x;
    int wave = tid >> 6, lane = tid & 63;
    int quad = lane >> 4, l16 = lane & 15;
    int wm = wave & 1, wn = wave >> 1;
    int bm = blockIdx.y * 128, bn = blockIdx.x * 128;

    f32x4 acc[4][4] = {};

    for (int kt = 0; kt < 8; ++kt) {
        int k0 = kt * 32;
#pragma unroll
        for (int i = 0; i < 2; ++i) {
            int chunk = tid + i * 256;          // 0..511
            int row = chunk >> 2;               // 0..127
            int coff = (chunk & 3) * 16;        // byte offset in 64B row
            int gr = bm + row; if (gr > M - 1) gr = M - 1;
            uint4 va = *(const uint4*)((const uint8_t*)A + ((size_t)gr * DIM + k0) * 2 + coff);
            *(uint4*)(ldsA + row * 64 + coff) = va;
            uint4 vb = *(const uint4*)((const uint8_t*)WT + ((size_t)(bn + row) * DIM + k0) * 2 + coff);
            *(uint4*)(ldsB + row * 64 + coff) = vb;
        }
        __syncthreads();
        bf16x8 afr[4], bfr[4];
#pragma unroll
        for (int t = 0; t < 4; ++t) {
            afr[t] = *(const bf16x8*)(ldsA + (wm * 64 + t * 16 + l16) * 64 + quad * 16);
            bfr[t] = *(const bf16x8*)(ldsB + (wn * 64 + t * 16 + l16) * 64 + quad * 16);
        }
#pragma unroll
        for (int tm = 0; tm < 4; ++tm)
#pragma unroll
            for (int tn = 0; tn < 4; ++tn)
                acc[tm][tn] = __builtin_amdgcn_mfma_f32_16x16x32_bf16(
                    afr[tm], bfr[tn], acc[tm][tn], 0, 0, 0);
        __syncthreads();
    }

    float bv[4];
#pragma unroll
    for (int tn = 0; tn < 4; ++tn) bv[tn] = bias[bn + wn * 64 + tn * 16 + l16];
#pragma unroll
    for (int tm = 0; tm < 4; ++tm) {
        int row0 = bm + wm * 64 + tm * 16 + quad * 4;
#pragma unroll
        for (int r = 0; r < 4; ++r) {
            int row = row0 + r;
            if (row < M) {
                float dsc = dis[row];
#pragma unroll
                for (int tn = 0; tn < 4; ++tn) {
                    int col = bn + wn * 64 + tn * 16 + l16;
                    C[(size_t)row * DIM + col] = f2bf((acc[tm][tn][r] + bv[tn]) * dsc);
                }
            }
        }
    }
}

// ---- pull aggregation (h pre-scaled by dis): z[n] = relu(dn*(sum_s h[s] + h[n]))
__global__ __launch_bounds__(256) void agg_kernel(const u16* __restrict__ h,
        const int* __restrict__ counts, const int* __restrict__ bucket,
        const float* __restrict__ dis, u16* __restrict__ z) {
    int wave = threadIdx.x >> 6, lane = threadIdx.x & 63;
    int n = blockIdx.x * 4 + wave;
    if (n >= N_NODES) return;
    int half = lane >> 5, l32 = lane & 31;
    int c = l32 * 8;
    float a[8];
    if (half == 0) {
        u16x8 v = *(const u16x8*)(h + (size_t)n * DIM + c);
#pragma unroll
        for (int j = 0; j < 8; ++j) a[j] = bf2f(v[j]);
    } else {
#pragma unroll
        for (int j = 0; j < 8; ++j) a[j] = 0.f;
    }
    int cnt = counts[n]; if (cnt > CAP) cnt = CAP;
    const int* bk = bucket + (size_t)n * CAP;
    int e = half;
    for (; e + 6 < cnt; e += 8) {
        int s0 = bk[e];
        int s1 = bk[e + 2];
        int s2 = bk[e + 4];
        int s3 = bk[e + 6];
        u16x8 v0 = *(const u16x8*)(h + (size_t)s0 * DIM + c);
        u16x8 v1 = *(const u16x8*)(h + (size_t)s1 * DIM + c);
        u16x8 v2 = *(const u16x8*)(h + (size_t)s2 * DIM + c);
        u16x8 v3 = *(const u16x8*)(h + (size_t)s3 * DIM + c);
#pragma unroll
        for (int j = 0; j < 8; ++j)
            a[j] += bf2f(v0[j]) + bf2f(v1[j]) + bf2f(v2[j]) + bf2f(v3[j]);
    }
    for (; e < cnt; e += 2) {
        int s = bk[e];
        u16x8 v = *(const u16x8*)(h + (size_t)s * DIM + c);
#pragma unroll
        for (int j = 0; j < 8; ++j) a[j] += bf2f(v[j]);
    }
#pragma unroll
    for (int j = 0; j < 8; ++j) a[j] += __shfl_xor(a[j], 32, 64);
    if (half == 0) {
        float dn = dis[n];
        u16x8 o;
#pragma unroll
        for (int j = 0; j < 8; ++j) o[j] = f2bf(fmaxf(a[j] * dn, 0.f));
        *(u16x8*)(z + (size_t)n * DIM + c) = o;
    }
}

// ---- pooling: out[g,:] += sum of z rows with batch==g (batch sorted) ----
// Block-level run-length accumulation, ~1-2 atomics per thread per block.
// (R9 lesson: per-element atomics into out = 880 us / 400 MB WRITE. Never again.)
__global__ void pool_kernel(const u16* __restrict__ z,
        const int* __restrict__ batch, float* __restrict__ out) {
    const int NPB = (N_NODES + 511) / 512;  // 98 nodes per block
    int n0 = blockIdx.x * NPB;
    int n1 = n0 + NPB; if (n1 > N_NODES) n1 = N_NODES;
    int t = threadIdx.x;
    float acc = 0.f;
    int gprev = -1;
    for (int n = n0; n < n1; ++n) {
        int g = batch[n];
        if (g != gprev) {
            if (gprev >= 0) atomicAdd(&out[gprev * DIM + t], acc);
            acc = 0.f; gprev = g;
        }
        acc += bf2f(z[(size_t)n * DIM + t]);
    }
    if (gprev >= 0) atomicAdd(&out[gprev * DIM + t], acc);
}

extern "C" void kernel_launch(void* const* d_in, const int* in_sizes, int n_in,
                              void* d_out, int out_size, void* d_ws, size_t ws_size,
                              hipStream_t stream) {
    const int*   seq   = (const int*)d_in[0];
    const int*   eidx  = (const int*)d_in[1];
    const int*   batch = (const int*)d_in[2];
    const float* emb   = (const float*)d_in[3];
    const float* W0    = (const float*)d_in[4];
    const float* b0    = (const float*)d_in[5];
    const float* W1    = (const float*)d_in[6];
    const float* b1    = (const float*)d_in[7];
    float* out = (float*)d_out;

    uint8_t* ws = (uint8_t*)d_ws;
    size_t off = 0;
    auto alloc = [&](size_t bytes) -> uint8_t* {
        uint8_t* p = ws + off;
        off += (bytes + 255) & ~(size_t)255;
        return p;
    };
    u16* emb_bf  = (u16*)alloc((size_t)VOCAB * DIM * 2);     // 51.2 MB
    u16* buf0    = (u16*)alloc((size_t)N_NODES * DIM * 2);   // 25.6 MB
    u16* buf1    = (u16*)alloc((size_t)N_NODES * DIM * 2);   // 25.6 MB
    int* bucket  = (int*)alloc((size_t)N_NODES * CAP * 4);   // 12.8 MB
    int* counts  = (int*)alloc((size_t)N_NODES * 4);
    float* dis   = (float*)alloc((size_t)N_NODES * 4);
    u16* WT0     = (u16*)alloc((size_t)DIM * DIM * 2);
    u16* WT1     = (u16*)alloc((size_t)DIM * DIM * 2);

    const int* esrc = eidx;
    const int* edst = eidx + N_EDGES;

    // 8 dispatches total
    prep_kernel<<<12500 + 128, 256, 0, stream>>>(emb, emb_bf, W0, WT0, W1, WT1,
                                                 counts, out);
    fill_kernel<<<(N_EDGES + 255) / 256, 256, 0, stream>>>(esrc, edst, counts, bucket);
    encode_kernel<<<(N_NODES + 3) / 4, 256, 0, stream>>>(seq, emb_bf, counts, dis, buf0);

    dim3 ggrid(2, (N_NODES + 127) / 128);  // (2, 391)
    gemm_kernel<<<ggrid, 256, 0, stream>>>(buf0, WT0, b0, dis, buf1, N_NODES);
    agg_kernel<<<(N_NODES + 3) / 4, 256, 0, stream>>>(buf1, counts, bucket, dis, buf0);
    gemm_kernel<<<ggrid, 256, 0, stream>>>(buf0, WT1, b1, dis, buf1, N_NODES);
    agg_kernel<<<(N_NODES + 3) / 4, 256, 0, stream>>>(buf1, counts, bucket, dis, buf0);

    pool_kernel<<<512, 256, 0, stream>>>(buf0, batch, out);
}